// Round 14
// baseline (257.779 us; speedup 1.0000x reference)
//
#include <hip/hip_runtime.h>

#define N_NODES 50000
#define N_EDGES 800000
#define N_B 2
#define N_C 64
#define BN_ROWS (N_B * N_NODES)
#define NRANGE 8
#define RSPAN 6250                      // 50000 / 8
#define FILL_CH 2048                    // edges per block-chunk
#define FILL_CHUNKS ((N_EDGES + FILL_CH - 1) / FILL_CH)   // 391

typedef __attribute__((ext_vector_type(8))) short short8;   // 8 bf16 = 4 VGPR
typedef __attribute__((ext_vector_type(4))) float f32x4;    // MFMA accum

__device__ inline unsigned short f2bf(float f) {
  unsigned int u = __float_as_uint(f);
  return (unsigned short)((u + 0x7fffu + ((u >> 16) & 1u)) >> 16);  // RNE
}
__device__ inline float bf2f(unsigned short h) { return __uint_as_float(((unsigned int)h) << 16); }
__device__ inline float lof(unsigned int u) { return __uint_as_float(u << 16); }
__device__ inline float hif(unsigned int u) { return __uint_as_float(u & 0xffff0000u); }

// ---------------- degree count (non-self-loop edges per source row) ----------
__global__ __launch_bounds__(256) void k_deg(const int* __restrict__ ei, int* __restrict__ deg) {
  int e = blockIdx.x * 256 + threadIdx.x;
  if (e >= N_EDGES) return;
  int r = ei[e];
  int c = ei[N_EDGES + e];
  if (r != c) atomicAdd(&deg[r], 1);
}

// ---------------- segment allocator: per-wave prefix + 1 atomic per wave -----
__global__ __launch_bounds__(256) void k_offsets(const int* __restrict__ deg, int* __restrict__ counter,
                                                 int* __restrict__ rowptr, int* __restrict__ cursor,
                                                 float* __restrict__ dis) {
  int n = blockIdx.x * 256 + threadIdx.x;
  int lane = threadIdx.x & 63;
  int d = (n < N_NODES) ? deg[n] : 0;
  int pre = d;
#pragma unroll
  for (int off = 1; off < 64; off <<= 1) {
    int v = __shfl_up(pre, off);
    if (lane >= off) pre += v;
  }
  int waveTotal = __shfl(pre, 63);
  int wbase = 0;
  if (lane == 63) wbase = atomicAdd(counter, waveTotal);
  wbase = __shfl(wbase, 63);
  if (n < N_NODES) {
    int off0 = wbase + pre - d;
    rowptr[n] = off0;
    cursor[n] = off0;
    dis[n] = d > 0 ? rsqrtf((float)d) : 0.0f;
  }
}

// ---------------- fill CSR: XCD-local row-range decomposition ----------------
// Round-13 diagnosis: WRITE_SIZE == one full 64B line per edge (55MB) even
// after halving the region -> NOT capacity; it's cross-XCD line ping-pong
// (each line's ~16 writes arrive from ~8 different XCDs' L2s -> ownership
// migrates per write, no combining). Here block b handles edge-chunk b>>3
// restricted to rows in range b&7 (6250 rows, ~400KB CSR segment). Coverage
// is exact for ANY block->XCD mapping (correctness G16-safe); with the
// practical %8 round-robin [m09], each segment is written by ONE XCD ->
// lines combine in its L2, one writeback each. ei re-streams (8x) are
// L3-resident after pass 1.
__global__ __launch_bounds__(256) void k_fill(const int* __restrict__ ei, const float* __restrict__ ew,
                                              const float* __restrict__ dis, int* __restrict__ cursor,
                                              unsigned int* __restrict__ ccv) {
  const int ridx = blockIdx.x & 7;
  const int chunk = blockIdx.x >> 3;
  const int rlo = ridx * RSPAN;
  const int rhi = rlo + RSPAN;
  const int e0 = chunk * FILL_CH + threadIdx.x;
#pragma unroll 1
  for (int i = 0; i < FILL_CH / 256; ++i) {
    int e = e0 + i * 256;
    if (e < N_EDGES) {
      int r = ei[e];
      if (r >= rlo && r < rhi) {
        int c = ei[N_EDGES + e];
        if (r != c) {
          float v = -dis[r] * ew[e] * dis[c];
          int pos = atomicAdd(&cursor[r], 1);
          ccv[pos] = (unsigned int)c | ((unsigned int)f2bf(v) << 16);
        }
      }
    }
  }
}

// ---------------- one-time weight pack into B-fragment order (global) --------
// Element offset = kt*2048 + c*512 + l*8 (kt=ktile 0..5, c=coltile, l=lane).
__global__ __launch_bounds__(256) void k_pack(const float* __restrict__ w, unsigned short* __restrict__ bpg) {
  int idx = blockIdx.x * 256 + threadIdx.x;  // 0..1535
  if (idx >= 1536) return;
  int kt = idx >> 8;
  int rem = idx & 255;
  int c = rem >> 6;
  int l = rem & 63;
  int ch = kt >> 1;
  int kbase = (kt & 1) * 32 + (l >> 4) * 8;
  int n = c * 16 + (l & 15);
  unsigned short* dst = &bpg[idx * 8];
#pragma unroll
  for (int j = 0; j < 8; ++j) {
    int k = kbase + j;
    float v;
    if (ch == 0)      v = w[k * 64 + n] - w[8192 + k * 64 + n];
    else if (ch == 1) v = w[4096 + k * 64 + n];
    else              v = 2.0f * w[8192 + k * 64 + n];
    dst[j] = f2bf(v);
  }
}

// ---------------- x (fp32) -> bf16 copy --------------------------------------
__global__ __launch_bounds__(256) void k_cvt(const float* __restrict__ x, unsigned short* __restrict__ xb) {
  int i = blockIdx.x * 256 + threadIdx.x;  // float4-quad index
  if (i >= BN_ROWS * 16) return;
  float4 v = ((const float4*)x)[i];
  ushort4 h;
  h.x = f2bf(v.x); h.y = f2bf(v.y); h.z = f2bf(v.z); h.w = f2bf(v.w);
  ((ushort4*)xb)[i] = h;
}

// ---------------- SPMM: dst[b,n,:] = sum_e lap_e * src[b,col_e,:] ------------
// One wave per NODE, BOTH batches. lane = (edge-slot g = l>>3) x (channel
// group cg = l&7). Per 8 edges: 1 per-lane 4B ccv load + 2 uint4 gathers.
#define UNPK_FMA(Q, A0, A1, A2, A3, A4, A5, A6, A7, V) \
  A0 += (V) * lof(Q.x); A1 += (V) * hif(Q.x); \
  A2 += (V) * lof(Q.y); A3 += (V) * hif(Q.y); \
  A4 += (V) * lof(Q.z); A5 += (V) * hif(Q.z); \
  A6 += (V) * lof(Q.w); A7 += (V) * hif(Q.w);

#define RED3(A) { A += __shfl_xor(A, 8); A += __shfl_xor(A, 16); A += __shfl_xor(A, 32); }

__global__ __launch_bounds__(256) void k_spmm(const unsigned short* __restrict__ src,
                                              unsigned short* __restrict__ dst,
                                              const int* __restrict__ rowptr, const int* __restrict__ deg,
                                              const unsigned int* __restrict__ ccv) {
  int n = (blockIdx.x * 256 + threadIdx.x) >> 6;
  int lane = threadIdx.x & 63;
  if (n >= N_NODES) return;
  const int g = lane >> 3;
  const int cg = lane & 7;
  const unsigned short* s0 = src;
  const unsigned short* s1 = src + (size_t)N_NODES * N_C;
  int r0 = rowptr[n];
  int end = r0 + deg[n];
  float a00 = 0, a01 = 0, a02 = 0, a03 = 0, a04 = 0, a05 = 0, a06 = 0, a07 = 0;
  float a10 = 0, a11 = 0, a12 = 0, a13 = 0, a14 = 0, a15 = 0, a16 = 0, a17 = 0;
#pragma unroll 2
  for (int i = r0; i < end; i += 8) {
    int idx = i + g;
    bool ok = idx < end;
    unsigned int pe = ccv[ok ? idx : (end - 1)];
    float val = ok ? hif(pe) : 0.0f;              // bf16 val sits in high half
    size_t off = (size_t)(pe & 0xFFFFu) * N_C + cg * 8;  // ushort units; 16B aligned
    uint4 q0 = *(const uint4*)(s0 + off);
    uint4 q1 = *(const uint4*)(s1 + off);
    UNPK_FMA(q0, a00, a01, a02, a03, a04, a05, a06, a07, val)
    UNPK_FMA(q1, a10, a11, a12, a13, a14, a15, a16, a17, val)
  }
  RED3(a00) RED3(a01) RED3(a02) RED3(a03) RED3(a04) RED3(a05) RED3(a06) RED3(a07)
  RED3(a10) RED3(a11) RED3(a12) RED3(a13) RED3(a14) RED3(a15) RED3(a16) RED3(a17)
  if (g == 0) {
    uint4 o;
    o.x = (unsigned)f2bf(a00) | ((unsigned)f2bf(a01) << 16);
    o.y = (unsigned)f2bf(a02) | ((unsigned)f2bf(a03) << 16);
    o.z = (unsigned)f2bf(a04) | ((unsigned)f2bf(a05) << 16);
    o.w = (unsigned)f2bf(a06) | ((unsigned)f2bf(a07) << 16);
    *(uint4*)(dst + (size_t)n * N_C + cg * 8) = o;
  } else if (g == 1) {
    uint4 o;
    o.x = (unsigned)f2bf(a10) | ((unsigned)f2bf(a11) << 16);
    o.y = (unsigned)f2bf(a12) | ((unsigned)f2bf(a13) << 16);
    o.z = (unsigned)f2bf(a14) | ((unsigned)f2bf(a15) << 16);
    o.w = (unsigned)f2bf(a16) | ((unsigned)f2bf(a17) << 16);
    *(uint4*)(dst + ((size_t)N_NODES + n) * N_C + cg * 8) = o;
  }
}

// ---------------- MFMA GEMM: out = [x|Tx1|Z] @ [W0-W2; W1; 2W2] + bias -------
// All three A-operands bf16 in ws. 128 rows/block; wave owns 32 rows. Stage:
// 6 coalesced 16B loads/thread -> conflict-free ds_write_b128. 12 independent
// 16B A-loads; per c-tile one B-frag read set, two independent 6-MFMA chains.
// C/D: col=lane&15, row=(lane>>4)*4+reg (m89).
__global__ __launch_bounds__(256) void k_gemm(const unsigned short* __restrict__ xb,
                                              const unsigned short* __restrict__ t1h,
                                              const unsigned short* __restrict__ zh,
                                              const unsigned short* __restrict__ bpg,
                                              const float* __restrict__ bias,
                                              float* __restrict__ out) {
  __shared__ unsigned short bp[12288];  // 24KB packed B fragments
  const int t = threadIdx.x;
#pragma unroll
  for (int i = 0; i < 6; ++i) {
    int idx = i * 256 + t;
    *(uint4*)&bp[idx * 8] = *(const uint4*)&bpg[idx * 8];
  }
  __syncthreads();

  const int wid = t >> 6;
  const int lane = t & 63;
  const size_t wbase = (size_t)blockIdx.x * 128 + (size_t)wid * 32;  // wave's 32 rows
  const int arow = lane & 15;
  const int ko = (lane >> 4) * 8;
  size_t rowA = wbase + arow;
  size_t rowB = wbase + 16 + arow;
  if (rowA > (size_t)(BN_ROWS - 1)) rowA = BN_ROWS - 1;  // clamped loads only
  if (rowB > (size_t)(BN_ROWS - 1)) rowB = BN_ROWS - 1;

  // ---- 12 independent 16B loads (6 per sub-tile) ----
  const unsigned short* xpA = xb + rowA * 64 + ko;
  const unsigned short* tpA = t1h + rowA * 64 + ko;
  const unsigned short* zpA = zh + rowA * 64 + ko;
  const unsigned short* xpB = xb + rowB * 64 + ko;
  const unsigned short* tpB = t1h + rowB * 64 + ko;
  const unsigned short* zpB = zh + rowB * 64 + ko;
  short8 axA0 = *(const short8*)(xpA);
  short8 axA1 = *(const short8*)(xpA + 32);
  short8 atA0 = *(const short8*)(tpA);
  short8 atA1 = *(const short8*)(tpA + 32);
  short8 azA0 = *(const short8*)(zpA);
  short8 azA1 = *(const short8*)(zpA + 32);
  short8 axB0 = *(const short8*)(xpB);
  short8 axB1 = *(const short8*)(xpB + 32);
  short8 atB0 = *(const short8*)(tpB);
  short8 atB1 = *(const short8*)(tpB + 32);
  short8 azB0 = *(const short8*)(zpB);
  short8 azB1 = *(const short8*)(zpB + 32);

  const int col = lane & 15;
  const int rgrp = lane >> 4;

#pragma unroll
  for (int c = 0; c < 4; ++c) {
    const unsigned short* bb = bp + c * 512;
    short8 b0 = *(const short8*)(bb + (0 * 256 + lane) * 8);
    short8 b1 = *(const short8*)(bb + (1 * 256 + lane) * 8);
    short8 b2 = *(const short8*)(bb + (2 * 256 + lane) * 8);
    short8 b3 = *(const short8*)(bb + (3 * 256 + lane) * 8);
    short8 b4 = *(const short8*)(bb + (4 * 256 + lane) * 8);
    short8 b5 = *(const short8*)(bb + (5 * 256 + lane) * 8);
    f32x4 accA = {0.f, 0.f, 0.f, 0.f};
    f32x4 accB = {0.f, 0.f, 0.f, 0.f};
    accA = __builtin_amdgcn_mfma_f32_16x16x32_bf16(axA0, b0, accA, 0, 0, 0);
    accB = __builtin_amdgcn_mfma_f32_16x16x32_bf16(axB0, b0, accB, 0, 0, 0);
    accA = __builtin_amdgcn_mfma_f32_16x16x32_bf16(axA1, b1, accA, 0, 0, 0);
    accB = __builtin_amdgcn_mfma_f32_16x16x32_bf16(axB1, b1, accB, 0, 0, 0);
    accA = __builtin_amdgcn_mfma_f32_16x16x32_bf16(atA0, b2, accA, 0, 0, 0);
    accB = __builtin_amdgcn_mfma_f32_16x16x32_bf16(atB0, b2, accB, 0, 0, 0);
    accA = __builtin_amdgcn_mfma_f32_16x16x32_bf16(atA1, b3, accA, 0, 0, 0);
    accB = __builtin_amdgcn_mfma_f32_16x16x32_bf16(atB1, b3, accB, 0, 0, 0);
    accA = __builtin_amdgcn_mfma_f32_16x16x32_bf16(azA0, b4, accA, 0, 0, 0);
    accB = __builtin_amdgcn_mfma_f32_16x16x32_bf16(azB0, b4, accB, 0, 0, 0);
    accA = __builtin_amdgcn_mfma_f32_16x16x32_bf16(azA1, b5, accA, 0, 0, 0);
    accB = __builtin_amdgcn_mfma_f32_16x16x32_bf16(azB1, b5, accB, 0, 0, 0);
    const float bcol = bias[c * 16 + col];
#pragma unroll
    for (int j = 0; j < 4; ++j) {
      size_t rA = wbase + (size_t)(rgrp * 4 + j);
      size_t rB = wbase + 16 + (size_t)(rgrp * 4 + j);
      if (rA < BN_ROWS) out[rA * 64 + c * 16 + col] = accA[j] + bcol;
      if (rB < BN_ROWS) out[rB * 64 + c * 16 + col] = accB[j] + bcol;
    }
  }
}

extern "C" void kernel_launch(void* const* d_in, const int* in_sizes, int n_in,
                              void* d_out, int out_size, void* d_ws, size_t ws_size,
                              hipStream_t stream) {
  const float* x = (const float*)d_in[0];
  const int* ei = (const int*)d_in[1];        // [2, E] int32
  const float* ew = (const float*)d_in[2];
  const float* w = (const float*)d_in[3];     // [3,64,64]
  const float* bias = (const float*)d_in[4];  // [64]
  float* out = (float*)d_out;

  // workspace layout (4-byte units)
  int* ws32 = (int*)d_ws;
  const size_t NA = 50048;  // padded N (16B-alignment preserved)
  int* deg = ws32;                          // [0..N) degrees, [N] = counter
  int* counter = deg + N_NODES;
  int* cursor = ws32 + NA;                  // free after k_fill -> reused for bpg
  float* dis = (float*)(cursor + NA);
  int* rowptr = (int*)(dis + NA);
  unsigned int* ccv = (unsigned int*)(rowptr + NA);                    // E uints (4B packed)
  unsigned short* xb = (unsigned short*)(ccv + N_EDGES);               // BN_ROWS*64 bf16
  unsigned short* t1h = xb + (size_t)BN_ROWS * N_C;                    // BN_ROWS*64 bf16
  unsigned short* zh = t1h + (size_t)BN_ROWS * N_C;                    // BN_ROWS*64 bf16
  unsigned short* bpg = (unsigned short*)cursor;                       // 24KB, aliases cursor
  const size_t NEED = ((size_t)(4 * NA + N_EDGES) + (size_t)BN_ROWS * N_C / 2 * 3) * 4;
  if (ws_size < NEED) return;  // clean fail instead of corruption

  hipMemsetAsync(deg, 0, (N_NODES + 1) * sizeof(int), stream);  // deg + counter
  k_cvt<<<(BN_ROWS * 16 + 255) / 256, 256, 0, stream>>>(x, xb);
  k_deg<<<(N_EDGES + 255) / 256, 256, 0, stream>>>(ei, deg);
  k_offsets<<<(N_NODES + 255) / 256, 256, 0, stream>>>(deg, counter, rowptr, cursor, dis);
  // XCD-local fill: block b -> chunk b>>3, row-range b&7
  k_fill<<<NRANGE * FILL_CHUNKS, 256, 0, stream>>>(ei, ew, dis, cursor, ccv);
  k_pack<<<6, 256, 0, stream>>>(w, bpg);  // cursor dead after k_fill
  // Tx1 = L x   (bf16, both batches per wave)
  k_spmm<<<(N_NODES * 64 + 255) / 256, 256, 0, stream>>>(xb, t1h, rowptr, deg, ccv);
  // Z = L Tx1   (bf16, into ws)
  k_spmm<<<(N_NODES * 64 + 255) / 256, 256, 0, stream>>>(t1h, zh, rowptr, deg, ccv);
  // out = [x|Tx1|Z] @ [W0-W2; W1; 2W2] + bias  (MFMA)
  k_gemm<<<(BN_ROWS + 127) / 128, 256, 0, stream>>>(xb, t1h, zh, bpg, bias, out);
}